// Round 8
// baseline (572.975 us; speedup 1.0000x reference)
//
#include <hip/hip_runtime.h>
#include <hip/hip_bf16.h>
#include <stdint.h>

// Problem constants
#define B_    4
#define CQ_   256
#define CKV_  256
#define NQ_   2048
#define NKV_  2048
#define H_    8
#define DK_   64
#define HD_   512   // H_*DK_

typedef __attribute__((ext_vector_type(8))) short bf16x8;
typedef __attribute__((ext_vector_type(4))) float f32x4;

__device__ __forceinline__ short f2bf(float f) {
    unsigned u = __builtin_bit_cast(unsigned, f);
    u = (u + 0x7FFFu + ((u >> 16) & 1u)) >> 16;   // RNE truncate to bf16
    return (short)u;
}

#define MFMA16(a, b, c) __builtin_amdgcn_mfma_f32_16x16x32_bf16((a), (b), (c), 0, 0, 0)

// Grid-wide barrier v2: monotonic counter, arrivals are the ONLY RMWs.
// Waiters poll with device-scope READ-ONLY loads (no line ownership ->
// no atomic-contention collapse; R7's atomicAdd(ctr,0) poll cost ~75us/barrier).
// All 512 blocks co-resident (launch_bounds(256,2): 2 blocks/CU x 256 CU).
// Bounded spin = graceful failure, never a hang.
__device__ __forceinline__ void megabarrier(unsigned* ctr, unsigned phase) {
    __syncthreads();
    if (threadIdx.x == 0) {
        __threadfence();                       // release: drain + make writes visible
        __hip_atomic_fetch_add(ctr, 1u, __ATOMIC_RELAXED, __HIP_MEMORY_SCOPE_AGENT);
        const unsigned target = 512u * phase;
        int t = 0;
        while (__hip_atomic_load(ctr, __ATOMIC_RELAXED, __HIP_MEMORY_SCOPE_AGENT) < target) {
            __builtin_amdgcn_s_sleep(32);      // ~2048 cyc backoff between polls
            if (++t > (1 << 17)) break;        // escape hatch vs deadlock
        }
    }
    __syncthreads();
    __threadfence();                           // acquire: invalidate stale caches
}

// One kernel, 512 blocks x 256 threads (2 blocks/CU co-resident).
//  P0: xkv f32->bf16 (1024 u) + pq folds (128 u)
//  P1: gram split-K=8 (512 u)   Gpart[kc][b][256][256] f32
//  P2: reduce-G (-> Gsum bf16, 1/64)  +  x_q transpose -> xqt bf16 (512 u)
//  P3: zgemm (512 u)            Zt[b][cq][h*256+c'] bf16
//  P4: ngemm split-K=8 (512 u)  Npart (aliases Gpart, dead after P2)
//  P5: reduce-N -> Nbf bf16
//  P6: final: out = gamma * N @ xqt^T + x_q
__global__ __launch_bounds__(256, 2) void mega_kernel(
    const float* __restrict__ x_q,
    const float* __restrict__ x_kv,
    const float* __restrict__ Wq,
    const float* __restrict__ Wk,
    const float* __restrict__ Wv,
    const float* __restrict__ Wo,
    const float* __restrict__ gamma,
    float* __restrict__ out,
    unsigned short* __restrict__ xkv_bf,
    unsigned short* __restrict__ xqt_bf,
    float* __restrict__ Gpart,
    float* __restrict__ Npart,
    unsigned short* __restrict__ Gsum,
    unsigned short* __restrict__ P,
    unsigned short* __restrict__ Qt,
    unsigned short* __restrict__ Zt,
    unsigned short* __restrict__ Nbf,
    unsigned* __restrict__ ctr)
{
    const int bid = blockIdx.x;     // 0..511
    const int tid = threadIdx.x;
    const int w = tid >> 6, L = tid & 63;
    const int r16 = L & 15, q = L >> 4;

    __shared__ float tile[64][65];  // 16.6 KB, used by P2 transpose only

    // ================= P0: xkv convert + pq folds =================
    for (int u = bid; u < 1152; u += 512) {
        if (u < 1024) {
            const size_t base = ((size_t)u * 256 + tid) * 8;
            const f32x4 v0 = *(const f32x4*)(x_kv + base);
            const f32x4 v1 = *(const f32x4*)(x_kv + base + 4);
            bf16x8 o;
            o[0] = f2bf(v0.x); o[1] = f2bf(v0.y); o[2] = f2bf(v0.z); o[3] = f2bf(v0.w);
            o[4] = f2bf(v1.x); o[5] = f2bf(v1.y); o[6] = f2bf(v1.z); o[7] = f2bf(v1.w);
            *(bf16x8*)(xkv_bf + base) = o;
        } else {
            const int lb0 = u - 1024;
            const bool isP = (lb0 < 64);
            const int lb = isP ? lb0 : lb0 - 64;
            const int h = lb >> 3;
            const int t = lb & 7;
            const int tm = (t >> 1) * 64;
            const int tn = (t & 1) * 128;
            const int wm = (w >> 1) * 32, wn = (w & 1) * 64;

            f32x4 acc[2][4];
#pragma unroll
            for (int mi = 0; mi < 2; ++mi)
#pragma unroll
                for (int ni = 0; ni < 4; ++ni) acc[mi][ni] = (f32x4){0.f,0.f,0.f,0.f};

#pragma unroll
            for (int kk = 0; kk < 2; ++kk) {
                const int d0 = kk * 32 + q * 8;
                bf16x8 a[2], bb[4];
                if (isP) {
#pragma unroll
                    for (int mi = 0; mi < 2; ++mi) {
                        const int m = tm + wm + mi * 16 + r16;
                        const f32x4* p = (const f32x4*)(Wo + (size_t)m * HD_ + h * 64 + d0);
                        f32x4 v0 = p[0], v1 = p[1];
                        a[mi][0]=f2bf(v0.x); a[mi][1]=f2bf(v0.y); a[mi][2]=f2bf(v0.z); a[mi][3]=f2bf(v0.w);
                        a[mi][4]=f2bf(v1.x); a[mi][5]=f2bf(v1.y); a[mi][6]=f2bf(v1.z); a[mi][7]=f2bf(v1.w);
                    }
#pragma unroll
                    for (int ni = 0; ni < 4; ++ni) {
                        const int n = tn + wn + ni * 16 + r16;
#pragma unroll
                        for (int j = 0; j < 8; ++j)
                            bb[ni][j] = f2bf(Wv[(size_t)(h * 64 + d0 + j) * CKV_ + n]);
                    }
                } else {
#pragma unroll
                    for (int mi = 0; mi < 2; ++mi) {
                        const int m = tm + wm + mi * 16 + r16;
#pragma unroll
                        for (int j = 0; j < 8; ++j)
                            a[mi][j] = f2bf(Wq[(size_t)(h * 64 + d0 + j) * CQ_ + m]);
                    }
#pragma unroll
                    for (int ni = 0; ni < 4; ++ni) {
                        const int n = tn + wn + ni * 16 + r16;
#pragma unroll
                        for (int j = 0; j < 8; ++j)
                            bb[ni][j] = f2bf(Wk[(size_t)(h * 64 + d0 + j) * CKV_ + n]);
                    }
                }
#pragma unroll
                for (int mi = 0; mi < 2; ++mi)
#pragma unroll
                    for (int ni = 0; ni < 4; ++ni)
                        acc[mi][ni] = MFMA16(a[mi], bb[ni], acc[mi][ni]);
            }

#pragma unroll
            for (int mi = 0; mi < 2; ++mi)
#pragma unroll
                for (int ni = 0; ni < 4; ++ni)
#pragma unroll
                    for (int r = 0; r < 4; ++r) {
                        const int m = tm + wm + mi * 16 + q * 4 + r;
                        const int n = tn + wn + ni * 16 + r16;
                        if (isP)  P [(size_t)m * 2048 + h * 256 + n] = (unsigned short)f2bf(acc[mi][ni][r]);
                        else      Qt[((size_t)h * 256 + m) * 256 + n] = (unsigned short)f2bf(acc[mi][ni][r]);
                    }
        }
    }
    megabarrier(ctr, 1);

    // ================= P1: gram split-K=8 =================
    {
        const int kc = bid & 7;
        const int t  = (bid >> 3) & 15;
        const int b  = bid >> 7;
        const int tm = (t >> 2) * 64;
        const int tn = (t & 3) * 64;
        const int wm = (w >> 1) * 32, wn = (w & 1) * 32;

        const unsigned short* Xb = xkv_bf + (size_t)b * CKV_ * NKV_;
        const unsigned short* A0 = Xb + (size_t)(tm + wm + r16) * NKV_;
        const unsigned short* A1 = A0 + (size_t)16 * NKV_;
        const unsigned short* B0 = Xb + (size_t)(tn + wn + r16) * NKV_;
        const unsigned short* B1 = B0 + (size_t)16 * NKV_;
        const int k0 = kc * 256 + q * 8;

        f32x4 acc[2][2];
#pragma unroll
        for (int mi = 0; mi < 2; ++mi)
#pragma unroll
            for (int ni = 0; ni < 2; ++ni) acc[mi][ni] = (f32x4){0.f,0.f,0.f,0.f};

        bf16x8 aC[2], bC[2];
        aC[0] = *(const bf16x8*)(A0 + k0);
        aC[1] = *(const bf16x8*)(A1 + k0);
        bC[0] = *(const bf16x8*)(B0 + k0);
        bC[1] = *(const bf16x8*)(B1 + k0);

#pragma unroll
        for (int kk = 0; kk < 8; ++kk) {
            bf16x8 aN[2], bN[2];
            if (kk < 7) {
                const int ko = k0 + (kk + 1) * 32;
                aN[0] = *(const bf16x8*)(A0 + ko);
                aN[1] = *(const bf16x8*)(A1 + ko);
                bN[0] = *(const bf16x8*)(B0 + ko);
                bN[1] = *(const bf16x8*)(B1 + ko);
            }
            acc[0][0] = MFMA16(aC[0], bC[0], acc[0][0]);
            acc[0][1] = MFMA16(aC[0], bC[1], acc[0][1]);
            acc[1][0] = MFMA16(aC[1], bC[0], acc[1][0]);
            acc[1][1] = MFMA16(aC[1], bC[1], acc[1][1]);
            aC[0] = aN[0]; aC[1] = aN[1]; bC[0] = bN[0]; bC[1] = bN[1];
        }

        float* Gp = Gpart + ((size_t)kc * B_ + b) * 65536;
#pragma unroll
        for (int mi = 0; mi < 2; ++mi)
#pragma unroll
            for (int ni = 0; ni < 2; ++ni)
#pragma unroll
                for (int r = 0; r < 4; ++r)
                    Gp[(tm + wm + mi * 16 + q * 4 + r) * 256 + tn + wn + ni * 16 + r16]
                        = acc[mi][ni][r];
    }
    megabarrier(ctr, 2);

    // ================= P2: reduce-G + x_q transpose =================
    {
        const int gtid = bid * 256 + tid;
        if (gtid < 65536) {
            const size_t base = (size_t)gtid * 4;
            f32x4 s = (f32x4){0.f,0.f,0.f,0.f};
#pragma unroll
            for (int kc = 0; kc < 8; ++kc) {
                f32x4 v = *(const f32x4*)(Gpart + (size_t)kc * 262144 + base);
                s.x += v.x; s.y += v.y; s.z += v.z; s.w += v.w;
            }
            const float sc = 1.0f / 64.0f;
            ushort4 o;
            o.x = (unsigned short)f2bf(s.x * sc);
            o.y = (unsigned short)f2bf(s.y * sc);
            o.z = (unsigned short)f2bf(s.z * sc);
            o.w = (unsigned short)f2bf(s.w * sc);
            *(ushort4*)(Gsum + base) = o;
        }

        const int b   = bid >> 7;
        const int t   = bid & 127;
        const int cq0 = (t & 3) * 64;
        const int n0  = (t >> 2) * 64;
        const float* src = x_q + (size_t)b * CQ_ * NQ_;
        const int r_l = tid >> 4;
        const int c_l = (tid & 15) * 4;
#pragma unroll
        for (int i = 0; i < 4; ++i) {
            const int row = r_l + 16 * i;
            const f32x4 v = *(const f32x4*)(src + (size_t)(cq0 + row) * NQ_ + n0 + c_l);
            tile[row][c_l] = v.x; tile[row][c_l + 1] = v.y;
            tile[row][c_l + 2] = v.z; tile[row][c_l + 3] = v.w;
        }
        __syncthreads();
        unsigned short* dst = xqt_bf + (size_t)b * NQ_ * CQ_;
        const int cq_l = (tid & 7) * 8;
#pragma unroll
        for (int j = 0; j < 2; ++j) {
            const int n_l = (tid >> 3) + 32 * j;
            bf16x8 o;
#pragma unroll
            for (int k = 0; k < 8; ++k) o[k] = f2bf(tile[cq_l + k][n_l]);
            *(bf16x8*)(dst + (size_t)(n0 + n_l) * CQ_ + cq0 + cq_l) = o;
        }
    }
    megabarrier(ctr, 3);

    // ================= P3: zgemm =================
    {
        const int t = bid & 15;
        const int h = (bid >> 4) & 7;
        const int b = bid >> 7;
        const int tm = (t >> 2) * 64;
        const int tn = (t & 3) * 64;
        const int wm = (w >> 1) * 32, wn = (w & 1) * 32;

        const unsigned short* Qh = Qt + (size_t)h * 65536;
        const unsigned short* Gb = Gsum + (size_t)b * 65536;
        const unsigned short* A0 = Qh + (size_t)(tm + wm + r16) * 256;
        const unsigned short* A1 = A0 + 16 * 256;
        const unsigned short* B0 = Gb + (size_t)(tn + wn + r16) * 256;
        const unsigned short* B1 = B0 + 16 * 256;
        const int k0 = q * 8;

        f32x4 acc[2][2];
#pragma unroll
        for (int mi = 0; mi < 2; ++mi)
#pragma unroll
            for (int ni = 0; ni < 2; ++ni) acc[mi][ni] = (f32x4){0.f,0.f,0.f,0.f};

        bf16x8 aC[2], bC[2];
        aC[0] = *(const bf16x8*)(A0 + k0);
        aC[1] = *(const bf16x8*)(A1 + k0);
        bC[0] = *(const bf16x8*)(B0 + k0);
        bC[1] = *(const bf16x8*)(B1 + k0);

#pragma unroll
        for (int kk = 0; kk < 8; ++kk) {
            bf16x8 aN[2], bN[2];
            if (kk < 7) {
                const int ko = k0 + (kk + 1) * 32;
                aN[0] = *(const bf16x8*)(A0 + ko);
                aN[1] = *(const bf16x8*)(A1 + ko);
                bN[0] = *(const bf16x8*)(B0 + ko);
                bN[1] = *(const bf16x8*)(B1 + ko);
            }
            acc[0][0] = MFMA16(aC[0], bC[0], acc[0][0]);
            acc[0][1] = MFMA16(aC[0], bC[1], acc[0][1]);
            acc[1][0] = MFMA16(aC[1], bC[0], acc[1][0]);
            acc[1][1] = MFMA16(aC[1], bC[1], acc[1][1]);
            aC[0] = aN[0]; aC[1] = aN[1]; bC[0] = bN[0]; bC[1] = bN[1];
        }

        unsigned short* Zb = Zt + (size_t)b * 256 * 2048;
#pragma unroll
        for (int mi = 0; mi < 2; ++mi)
#pragma unroll
            for (int ni = 0; ni < 2; ++ni)
#pragma unroll
                for (int r = 0; r < 4; ++r) {
                    const int m = tm + wm + mi * 16 + q * 4 + r;
                    const int n = tn + wn + ni * 16 + r16;
                    Zb[(size_t)m * 2048 + h * 256 + n] = (unsigned short)f2bf(acc[mi][ni][r]);
                }
    }
    megabarrier(ctr, 4);

    // ================= P4: ngemm split-K=8 =================
    {
        const int t  = bid & 15;
        const int sk = (bid >> 4) & 7;
        const int b  = bid >> 7;
        const int tm = (t >> 2) * 64;
        const int tn = (t & 3) * 64;
        const int wm = (w >> 1) * 32, wn = (w & 1) * 32;

        const unsigned short* Zb = Zt + (size_t)b * 256 * 2048;
        const unsigned short* A0 = P  + (size_t)(tm + wm + r16) * 2048;
        const unsigned short* A1 = A0 + 16 * 2048;
        const unsigned short* B0 = Zb + (size_t)(tn + wn + r16) * 2048;
        const unsigned short* B1 = B0 + 16 * 2048;
        const int k0 = sk * 256 + q * 8;

        f32x4 acc[2][2];
#pragma unroll
        for (int mi = 0; mi < 2; ++mi)
#pragma unroll
            for (int ni = 0; ni < 2; ++ni) acc[mi][ni] = (f32x4){0.f,0.f,0.f,0.f};

        bf16x8 aC[2], bC[2];
        aC[0] = *(const bf16x8*)(A0 + k0);
        aC[1] = *(const bf16x8*)(A1 + k0);
        bC[0] = *(const bf16x8*)(B0 + k0);
        bC[1] = *(const bf16x8*)(B1 + k0);

#pragma unroll
        for (int kk = 0; kk < 8; ++kk) {
            bf16x8 aN[2], bN[2];
            if (kk < 7) {
                const int ko = k0 + (kk + 1) * 32;
                aN[0] = *(const bf16x8*)(A0 + ko);
                aN[1] = *(const bf16x8*)(A1 + ko);
                bN[0] = *(const bf16x8*)(B0 + ko);
                bN[1] = *(const bf16x8*)(B1 + ko);
            }
            acc[0][0] = MFMA16(aC[0], bC[0], acc[0][0]);
            acc[0][1] = MFMA16(aC[0], bC[1], acc[0][1]);
            acc[1][0] = MFMA16(aC[1], bC[0], acc[1][0]);
            acc[1][1] = MFMA16(aC[1], bC[1], acc[1][1]);
            aC[0] = aN[0]; aC[1] = aN[1]; bC[0] = bN[0]; bC[1] = bN[1];
        }

        float* Np = Npart + ((size_t)sk * B_ + b) * 65536;
#pragma unroll
        for (int mi = 0; mi < 2; ++mi)
#pragma unroll
            for (int ni = 0; ni < 2; ++ni)
#pragma unroll
                for (int r = 0; r < 4; ++r)
                    Np[(tm + wm + mi * 16 + q * 4 + r) * 256 + tn + wn + ni * 16 + r16]
                        = acc[mi][ni][r];
    }
    megabarrier(ctr, 5);

    // ================= P5: reduce-N =================
    {
        const int gtid = bid * 256 + tid;
        if (gtid < 65536) {
            const size_t base = (size_t)gtid * 4;
            f32x4 s = (f32x4){0.f,0.f,0.f,0.f};
#pragma unroll
            for (int sk = 0; sk < 8; ++sk) {
                f32x4 v = *(const f32x4*)(Npart + (size_t)sk * 262144 + base);
                s.x += v.x; s.y += v.y; s.z += v.z; s.w += v.w;
            }
            ushort4 o;
            o.x = (unsigned short)f2bf(s.x);
            o.y = (unsigned short)f2bf(s.y);
            o.z = (unsigned short)f2bf(s.z);
            o.w = (unsigned short)f2bf(s.w);
            *(ushort4*)(Nbf + base) = o;
        }
    }
    megabarrier(ctr, 6);

    // ================= P6: final =================
    {
        const int nblk = (bid & 31) * 64;
        const int cblk = ((bid >> 5) & 3) * 64;
        const int b    = bid >> 7;
        const int wc = (w >> 1) * 32;
        const int wn = (w & 1) * 32;

        const unsigned short* Nb = Nbf + (size_t)b * 65536;
        const unsigned short* Xq = xqt_bf + (size_t)b * NQ_ * CQ_;
        const float* Xb = x_q + (size_t)b * CQ_ * NQ_;
        const float g = gamma[0];

        const unsigned short* A0 = Nb + (size_t)(cblk + wc + r16) * 256;
        const unsigned short* A1 = A0 + 16 * 256;
        const unsigned short* B0 = Xq + (size_t)(nblk + wn + r16) * 256;
        const unsigned short* B1 = B0 + 16 * 256;
        const int k0 = q * 8;

        f32x4 acc[2][2];
#pragma unroll
        for (int mi = 0; mi < 2; ++mi)
#pragma unroll
            for (int ni = 0; ni < 2; ++ni) acc[mi][ni] = (f32x4){0.f,0.f,0.f,0.f};

        bf16x8 aC[2], bC[2];
        aC[0] = *(const bf16x8*)(A0 + k0);
        aC[1] = *(const bf16x8*)(A1 + k0);
        bC[0] = *(const bf16x8*)(B0 + k0);
        bC[1] = *(const bf16x8*)(B1 + k0);

#pragma unroll
        for (int kk = 0; kk < 8; ++kk) {
            bf16x8 aN[2], bN[2];
            if (kk < 7) {
                const int ko = k0 + (kk + 1) * 32;
                aN[0] = *(const bf16x8*)(A0 + ko);
                aN[1] = *(const bf16x8*)(A1 + ko);
                bN[0] = *(const bf16x8*)(B0 + ko);
                bN[1] = *(const bf16x8*)(B1 + ko);
            }
            acc[0][0] = MFMA16(aC[0], bC[0], acc[0][0]);
            acc[0][1] = MFMA16(aC[0], bC[1], acc[0][1]);
            acc[1][0] = MFMA16(aC[1], bC[0], acc[1][0]);
            acc[1][1] = MFMA16(aC[1], bC[1], acc[1][1]);
            aC[0] = aN[0]; aC[1] = aN[1]; bC[0] = bN[0]; bC[1] = bN[1];
        }

#pragma unroll
        for (int mi = 0; mi < 2; ++mi)
#pragma unroll
            for (int ni = 0; ni < 2; ++ni)
#pragma unroll
                for (int r = 0; r < 4; ++r) {
                    const int c = cblk + wc + mi * 16 + q * 4 + r;
                    const int n = nblk + wn + ni * 16 + r16;
                    const size_t idx = ((size_t)b * CQ_ + c) * NQ_ + n;
                    out[idx] = g * acc[mi][ni][r] + Xb[(size_t)c * NQ_ + n];
                }
    }
}

// -------------------------------------------------------------------------
extern "C" void kernel_launch(void* const* d_in, const int* in_sizes, int n_in,
                              void* d_out, int out_size, void* d_ws, size_t ws_size,
                              hipStream_t stream) {
    const float* x_q   = (const float*)d_in[0];
    const float* x_kv  = (const float*)d_in[1];
    const float* Wq    = (const float*)d_in[2];
    const float* Wk    = (const float*)d_in[3];
    const float* Wv    = (const float*)d_in[4];
    const float* Wo    = (const float*)d_in[5];
    const float* gamma = (const float*)d_in[6];
    float* out = (float*)d_out;

    char* ws = (char*)d_ws;
    // ws layout (bytes):
    //   xkv_bf bf16 [4][256][2048]         0 ..  4194304
    //   xqt_bf bf16 [4][2048][256]   4194304 ..  8388608
    //   Gpart  f32  [8][4][256][256] 8388608 .. 16777216  (aliased by Npart after P2)
    //   Gsum   bf16 [4][256][256]   16777216 .. 17301504
    //   Nbf    bf16 [4][256][256]   17301504 .. 17825792
    //   P      bf16 [256][2048]     17825792 .. 18874368
    //   Qt     bf16 [8][256][256]   18874368 .. 19922944
    //   Zt     bf16 [4][256][2048]  19922944 .. 24117248
    //   ctr    u32                  24117248 .. 24117312
    unsigned short* xkv_bf = (unsigned short*)(ws);
    unsigned short* xqt_bf = (unsigned short*)(ws + 4194304);
    float*          Gpart  = (float*)(ws + 8388608);
    float*          Npart  = (float*)(ws + 8388608);
    unsigned short* Gsum   = (unsigned short*)(ws + 16777216);
    unsigned short* Nbf    = (unsigned short*)(ws + 17301504);
    unsigned short* P      = (unsigned short*)(ws + 17825792);
    unsigned short* Qt     = (unsigned short*)(ws + 18874368);
    unsigned short* Zt     = (unsigned short*)(ws + 19922944);
    unsigned*       ctr    = (unsigned*)(ws + 24117248);

    hipMemsetAsync(ctr, 0, 64, stream);
    mega_kernel<<<dim3(512), dim3(256), 0, stream>>>(
        x_q, x_kv, Wq, Wk, Wv, Wo, gamma, out,
        xkv_bf, xqt_bf, Gpart, Npart, Gsum, P, Qt, Zt, Nbf, ctr);
}

// Round 9
// 141.956 us; speedup vs baseline: 4.0363x; 4.0363x over previous
//
#include <hip/hip_runtime.h>
#include <hip/hip_bf16.h>
#include <stdint.h>

// Problem constants
#define B_    4
#define CQ_   256
#define CKV_  256
#define NQ_   2048
#define NKV_  2048
#define H_    8
#define DK_   64
#define HD_   512   // H_*DK_

typedef __attribute__((ext_vector_type(8))) short bf16x8;
typedef __attribute__((ext_vector_type(4))) float f32x4;

__device__ __forceinline__ short f2bf(float f) {
    unsigned u = __builtin_bit_cast(unsigned, f);
    u = (u + 0x7FFFu + ((u >> 16) & 1u)) >> 16;   // RNE truncate to bf16
    return (short)u;
}

__device__ __forceinline__ bf16x8 cvt8(const f32x4 a, const f32x4 b) {
    bf16x8 o;
    o[0] = f2bf(a.x); o[1] = f2bf(a.y); o[2] = f2bf(a.z); o[3] = f2bf(a.w);
    o[4] = f2bf(b.x); o[5] = f2bf(b.y); o[6] = f2bf(b.z); o[7] = f2bf(b.w);
    return o;
}

#define MFMA16(a, b, c) __builtin_amdgcn_mfma_f32_16x16x32_bf16((a), (b), (c), 0, 0, 0)

// -------------------------------------------------------------------------
// Kernel 1: prep.  [0,512): x_q transpose -> xqt_bf [b][n][cq] bf16
//                  [512,640): pq folds (P = Wo_h*Wv_h; Qt = Wq^T*Wk per h)
//                  [640,656): zero Gsum32+Nsum32 (2 MB contiguous)
// -------------------------------------------------------------------------
__global__ __launch_bounds__(256) void prep_kernel(
    const float* __restrict__ x_q,
    const float* __restrict__ Wq,
    const float* __restrict__ Wk,
    const float* __restrict__ Wv,
    const float* __restrict__ Wo,
    unsigned short* __restrict__ xqt_bf,
    unsigned short* __restrict__ P,
    unsigned short* __restrict__ Qt,
    float* __restrict__ zero_base)   // Gsum32 (1MB) ++ Nsum32 (1MB)
{
    const int tid = threadIdx.x;
    const int bid = blockIdx.x;

    if (bid < 512) {
        // ---- x_q transpose (64x64 tile via LDS) ----
        const int b   = bid >> 7;
        const int t   = bid & 127;
        const int cq0 = (t & 3) * 64;
        const int n0  = (t >> 2) * 64;

        __shared__ float tile[64][65];
        const float* src = x_q + (size_t)b * CQ_ * NQ_;
        const int r_l = tid >> 4;
        const int c_l = (tid & 15) * 4;
#pragma unroll
        for (int i = 0; i < 4; ++i) {
            const int row = r_l + 16 * i;
            const f32x4 v = *(const f32x4*)(src + (size_t)(cq0 + row) * NQ_ + n0 + c_l);
            tile[row][c_l] = v.x; tile[row][c_l + 1] = v.y;
            tile[row][c_l + 2] = v.z; tile[row][c_l + 3] = v.w;
        }
        __syncthreads();
        unsigned short* dst = xqt_bf + (size_t)b * NQ_ * CQ_;
        const int cq_l = (tid & 7) * 8;
#pragma unroll
        for (int j = 0; j < 2; ++j) {
            const int n_l = (tid >> 3) + 32 * j;
            bf16x8 o;
#pragma unroll
            for (int k = 0; k < 8; ++k) o[k] = f2bf(tile[cq_l + k][n_l]);
            *(bf16x8*)(dst + (size_t)(n0 + n_l) * CQ_ + cq0 + cq_l) = o;
        }
        return;
    }

    if (bid >= 640) {
        // ---- zero Gsum32 + Nsum32 ----
        const int i = bid - 640;                 // 0..15, 131072 B each
        float* p = zero_base + (size_t)i * 32768;
        const f32x4 z = (f32x4){0.f, 0.f, 0.f, 0.f};
#pragma unroll
        for (int j = 0; j < 32; ++j)
            *(f32x4*)(p + (size_t)j * 1024 + tid * 4) = z;
        return;
    }

    // ---- pq folds ----
    const int lb0 = bid - 512;
    const bool isP = (lb0 < 64);
    const int lb = isP ? lb0 : lb0 - 64;
    const int h = lb >> 3;
    const int t = lb & 7;
    const int tm = (t >> 1) * 64;
    const int tn = (t & 1) * 128;
    const int w = tid >> 6, L = tid & 63;
    const int r16 = L & 15, q = L >> 4;
    const int wm = (w >> 1) * 32, wn = (w & 1) * 64;

    f32x4 acc[2][4];
#pragma unroll
    for (int mi = 0; mi < 2; ++mi)
#pragma unroll
        for (int ni = 0; ni < 4; ++ni) acc[mi][ni] = (f32x4){0.f,0.f,0.f,0.f};

#pragma unroll
    for (int kk = 0; kk < 2; ++kk) {
        const int d0 = kk * 32 + q * 8;
        bf16x8 a[2], bb[4];
        if (isP) {
#pragma unroll
            for (int mi = 0; mi < 2; ++mi) {
                const int m = tm + wm + mi * 16 + r16;
                const f32x4* p = (const f32x4*)(Wo + (size_t)m * HD_ + h * 64 + d0);
                a[mi] = cvt8(p[0], p[1]);
            }
#pragma unroll
            for (int ni = 0; ni < 4; ++ni) {
                const int n = tn + wn + ni * 16 + r16;
#pragma unroll
                for (int j = 0; j < 8; ++j)
                    bb[ni][j] = f2bf(Wv[(size_t)(h * 64 + d0 + j) * CKV_ + n]);
            }
        } else {
#pragma unroll
            for (int mi = 0; mi < 2; ++mi) {
                const int m = tm + wm + mi * 16 + r16;
#pragma unroll
                for (int j = 0; j < 8; ++j)
                    a[mi][j] = f2bf(Wq[(size_t)(h * 64 + d0 + j) * CQ_ + m]);
            }
#pragma unroll
            for (int ni = 0; ni < 4; ++ni) {
                const int n = tn + wn + ni * 16 + r16;
#pragma unroll
                for (int j = 0; j < 8; ++j)
                    bb[ni][j] = f2bf(Wk[(size_t)(h * 64 + d0 + j) * CKV_ + n]);
            }
        }
#pragma unroll
        for (int mi = 0; mi < 2; ++mi)
#pragma unroll
            for (int ni = 0; ni < 4; ++ni)
                acc[mi][ni] = MFMA16(a[mi], bb[ni], acc[mi][ni]);
    }

#pragma unroll
    for (int mi = 0; mi < 2; ++mi)
#pragma unroll
        for (int ni = 0; ni < 4; ++ni)
#pragma unroll
            for (int r = 0; r < 4; ++r) {
                const int m = tm + wm + mi * 16 + q * 4 + r;
                const int n = tn + wn + ni * 16 + r16;
                if (isP)  P [(size_t)m * 2048 + h * 256 + n] = (unsigned short)f2bf(acc[mi][ni][r]);
                else      Qt[((size_t)h * 256 + m) * 256 + n] = (unsigned short)f2bf(acc[mi][ni][r]);
            }
}

// -------------------------------------------------------------------------
// Kernel 2: gram.  Gsum32_b[c][c'] += (1/64)*sum_{n chunk} x[c][n]*x[c'][n]
// Reads x_kv f32 directly (in-loop cvt).  64x64 tiles, split-K=8,
// grid (8,16,4)=512 blocks.  Epilogue: f32 atomicAdd (Gsum32 pre-zeroed).
// -------------------------------------------------------------------------
__global__ __launch_bounds__(256) void gram_kernel(
    const float* __restrict__ x_kv,
    float* __restrict__ Gsum32)
{
    const int kc = blockIdx.x;            // 0..7
    const int t  = blockIdx.y;            // 0..15
    const int b  = blockIdx.z;
    const int tid = threadIdx.x;
    const int w = tid >> 6, L = tid & 63;
    const int r16 = L & 15, q = L >> 4;
    const int tm = (t >> 2) * 64;
    const int tn = (t & 3) * 64;
    const int wm = (w >> 1) * 32, wn = (w & 1) * 32;

    const float* Xb = x_kv + (size_t)b * CKV_ * NKV_;
    const float* base[4];
    base[0] = Xb + (size_t)(tm + wm + r16) * NKV_;
    base[1] = base[0] + (size_t)16 * NKV_;
    base[2] = Xb + (size_t)(tn + wn + r16) * NKV_;
    base[3] = base[2] + (size_t)16 * NKV_;
    const int k0 = kc * 256 + q * 8;

    f32x4 acc[2][2];
#pragma unroll
    for (int mi = 0; mi < 2; ++mi)
#pragma unroll
        for (int ni = 0; ni < 2; ++ni) acc[mi][ni] = (f32x4){0.f,0.f,0.f,0.f};

    f32x4 cur[4][2], nxt[4][2];
#pragma unroll
    for (int f = 0; f < 4; ++f) {
        cur[f][0] = *(const f32x4*)(base[f] + k0);
        cur[f][1] = *(const f32x4*)(base[f] + k0 + 4);
    }

#pragma unroll
    for (int kk = 0; kk < 8; ++kk) {
        if (kk < 7) {
            const int ko = k0 + (kk + 1) * 32;
#pragma unroll
            for (int f = 0; f < 4; ++f) {
                nxt[f][0] = *(const f32x4*)(base[f] + ko);
                nxt[f][1] = *(const f32x4*)(base[f] + ko + 4);
            }
        }
        const bf16x8 a0 = cvt8(cur[0][0], cur[0][1]);
        const bf16x8 a1 = cvt8(cur[1][0], cur[1][1]);
        const bf16x8 b0 = cvt8(cur[2][0], cur[2][1]);
        const bf16x8 b1 = cvt8(cur[3][0], cur[3][1]);
        acc[0][0] = MFMA16(a0, b0, acc[0][0]);
        acc[0][1] = MFMA16(a0, b1, acc[0][1]);
        acc[1][0] = MFMA16(a1, b0, acc[1][0]);
        acc[1][1] = MFMA16(a1, b1, acc[1][1]);
#pragma unroll
        for (int f = 0; f < 4; ++f) { cur[f][0] = nxt[f][0]; cur[f][1] = nxt[f][1]; }
    }

    float* Gb = Gsum32 + (size_t)b * 65536;
    const float sc = 1.0f / 64.0f;
#pragma unroll
    for (int mi = 0; mi < 2; ++mi)
#pragma unroll
        for (int ni = 0; ni < 2; ++ni)
#pragma unroll
            for (int r = 0; r < 4; ++r) {
                const int row = tm + wm + mi * 16 + q * 4 + r;
                const int col = tn + wn + ni * 16 + r16;
                atomicAdd(&Gb[row * 256 + col], acc[mi][ni][r] * sc);
            }
}

// -------------------------------------------------------------------------
// Kernel 3: zgemm.  Zt_b[cq][h*256+c'] = sum_{c''} Qt[(h,cq)][c'']*G_b[c'][c'']
// A = Qt bf16 (dbuf); B = Gsum32 f32 rows (G symmetric, in-loop cvt).
// 64x64 tiles, grid (16,8,4)=512 blocks.
// -------------------------------------------------------------------------
__global__ __launch_bounds__(256) void zgemm_kernel(
    const unsigned short* __restrict__ Qt,
    const float* __restrict__ Gsum32,
    unsigned short* __restrict__ Zt)
{
    const int t = blockIdx.x;   // 0..15
    const int h = blockIdx.y;
    const int b = blockIdx.z;
    const int tid = threadIdx.x;
    const int w = tid >> 6, L = tid & 63;
    const int r16 = L & 15, q = L >> 4;
    const int tm = (t >> 2) * 64;
    const int tn = (t & 3) * 64;
    const int wm = (w >> 1) * 32, wn = (w & 1) * 32;

    const unsigned short* Qh = Qt + (size_t)h * 65536;
    const float* Gb = Gsum32 + (size_t)b * 65536;
    const unsigned short* A0 = Qh + (size_t)(tm + wm + r16) * 256;
    const unsigned short* A1 = A0 + 16 * 256;
    const float* Bb[2];
    Bb[0] = Gb + (size_t)(tn + wn + r16) * 256;
    Bb[1] = Bb[0] + 16 * 256;
    const int k0 = q * 8;

    f32x4 acc[2][2];
#pragma unroll
    for (int mi = 0; mi < 2; ++mi)
#pragma unroll
        for (int ni = 0; ni < 2; ++ni) acc[mi][ni] = (f32x4){0.f,0.f,0.f,0.f};

    bf16x8 aC[2];
    f32x4 bcur[2][2], bnxt[2][2];
    aC[0] = *(const bf16x8*)(A0 + k0);
    aC[1] = *(const bf16x8*)(A1 + k0);
#pragma unroll
    for (int f = 0; f < 2; ++f) {
        bcur[f][0] = *(const f32x4*)(Bb[f] + k0);
        bcur[f][1] = *(const f32x4*)(Bb[f] + k0 + 4);
    }

#pragma unroll
    for (int kk = 0; kk < 8; ++kk) {
        bf16x8 aN[2];
        if (kk < 7) {
            const int ko = k0 + (kk + 1) * 32;
            aN[0] = *(const bf16x8*)(A0 + ko);
            aN[1] = *(const bf16x8*)(A1 + ko);
#pragma unroll
            for (int f = 0; f < 2; ++f) {
                bnxt[f][0] = *(const f32x4*)(Bb[f] + ko);
                bnxt[f][1] = *(const f32x4*)(Bb[f] + ko + 4);
            }
        }
        const bf16x8 b0 = cvt8(bcur[0][0], bcur[0][1]);
        const bf16x8 b1 = cvt8(bcur[1][0], bcur[1][1]);
        acc[0][0] = MFMA16(aC[0], b0, acc[0][0]);
        acc[0][1] = MFMA16(aC[0], b1, acc[0][1]);
        acc[1][0] = MFMA16(aC[1], b0, acc[1][0]);
        acc[1][1] = MFMA16(aC[1], b1, acc[1][1]);
        aC[0] = aN[0]; aC[1] = aN[1];
#pragma unroll
        for (int f = 0; f < 2; ++f) { bcur[f][0] = bnxt[f][0]; bcur[f][1] = bnxt[f][1]; }
    }

    unsigned short* Zb = Zt + (size_t)b * 256 * 2048;
#pragma unroll
    for (int mi = 0; mi < 2; ++mi)
#pragma unroll
        for (int ni = 0; ni < 2; ++ni)
#pragma unroll
            for (int r = 0; r < 4; ++r) {
                const int m = tm + wm + mi * 16 + q * 4 + r;       // cq
                const int n = tn + wn + ni * 16 + r16;             // c'
                Zb[(size_t)m * 2048 + h * 256 + n] = (unsigned short)f2bf(acc[mi][ni][r]);
            }
}

// -------------------------------------------------------------------------
// Kernel 4: ngemm.  Nsum32_b[c][cq] += sum_{k chunk} P[c][k]*Zt_b[cq][k]
// 64x64 tiles, split-K=8 (chunks of 256), grid (16,8,4)=512 blocks.
// Epilogue: f32 atomicAdd (Nsum32 pre-zeroed by prep).
// -------------------------------------------------------------------------
__global__ __launch_bounds__(256) void ngemm_kernel(
    const unsigned short* __restrict__ P,
    const unsigned short* __restrict__ Zt,
    float* __restrict__ Nsum32)
{
    const int t  = blockIdx.x;  // 0..15
    const int sk = blockIdx.y;  // 0..7
    const int b  = blockIdx.z;
    const int tid = threadIdx.x;
    const int w = tid >> 6, L = tid & 63;
    const int r16 = L & 15, q = L >> 4;
    const int tm = (t >> 2) * 64;
    const int tn = (t & 3) * 64;
    const int wm = (w >> 1) * 32, wn = (w & 1) * 32;

    const unsigned short* Zb = Zt + (size_t)b * 256 * 2048;
    const unsigned short* A0 = P  + (size_t)(tm + wm + r16) * 2048;
    const unsigned short* A1 = A0 + 16 * 2048;
    const unsigned short* B0 = Zb + (size_t)(tn + wn + r16) * 2048;
    const unsigned short* B1 = B0 + 16 * 2048;
    const int k0 = sk * 256 + q * 8;

    f32x4 acc[2][2];
#pragma unroll
    for (int mi = 0; mi < 2; ++mi)
#pragma unroll
        for (int ni = 0; ni < 2; ++ni) acc[mi][ni] = (f32x4){0.f,0.f,0.f,0.f};

    bf16x8 aC[2], bC[2];
    aC[0] = *(const bf16x8*)(A0 + k0);
    aC[1] = *(const bf16x8*)(A1 + k0);
    bC[0] = *(const bf16x8*)(B0 + k0);
    bC[1] = *(const bf16x8*)(B1 + k0);

#pragma unroll
    for (int kk = 0; kk < 8; ++kk) {
        bf16x8 aN[2], bN[2];
        if (kk < 7) {
            const int ko = k0 + (kk + 1) * 32;
            aN[0] = *(const bf16x8*)(A0 + ko);
            aN[1] = *(const bf16x8*)(A1 + ko);
            bN[0] = *(const bf16x8*)(B0 + ko);
            bN[1] = *(const bf16x8*)(B1 + ko);
        }
        acc[0][0] = MFMA16(aC[0], bC[0], acc[0][0]);
        acc[0][1] = MFMA16(aC[0], bC[1], acc[0][1]);
        acc[1][0] = MFMA16(aC[1], bC[0], acc[1][0]);
        acc[1][1] = MFMA16(aC[1], bC[1], acc[1][1]);
        aC[0] = aN[0]; aC[1] = aN[1]; bC[0] = bN[0]; bC[1] = bN[1];
    }

    float* Nb = Nsum32 + (size_t)b * 65536;
#pragma unroll
    for (int mi = 0; mi < 2; ++mi)
#pragma unroll
        for (int ni = 0; ni < 2; ++ni)
#pragma unroll
            for (int r = 0; r < 4; ++r) {
                const int row = tm + wm + mi * 16 + q * 4 + r;     // c
                const int col = tn + wn + ni * 16 + r16;           // cq
                atomicAdd(&Nb[row * 256 + col], acc[mi][ni][r]);
            }
}

// -------------------------------------------------------------------------
// Kernel 5: final.  out[b][c][n] = g*sum_cq N[c][cq]*xqt[n][cq] + x_q[c][n]
// A = Nsum32 f32 rows (in-loop cvt); B = xqt bf16 (dbuf).
// 64x64 tiles, grid (32,4,4)=512 blocks.
// -------------------------------------------------------------------------
__global__ __launch_bounds__(256) void final_kernel(
    const float* __restrict__ Nsum32,
    const unsigned short* __restrict__ xqt_bf,
    const float* __restrict__ x_q,
    const float* __restrict__ gamma,
    float* __restrict__ out)
{
    const int nblk = blockIdx.x * 64;
    const int cblk = blockIdx.y * 64;
    const int b    = blockIdx.z;
    const int tid  = threadIdx.x;
    const int w = tid >> 6, L = tid & 63;
    const int r16 = L & 15, q = L >> 4;
    const int wc = (w >> 1) * 32;
    const int wn = (w & 1) * 32;

    const float* Nb = Nsum32 + (size_t)b * 65536;
    const unsigned short* Xq = xqt_bf + (size_t)b * NQ_ * CQ_;
    const float* Xb = x_q + (size_t)b * CQ_ * NQ_;
    const float g = gamma[0];

    const float* Af[2];
    Af[0] = Nb + (size_t)(cblk + wc + r16) * 256;
    Af[1] = Af[0] + 16 * 256;
    const unsigned short* B0 = Xq + (size_t)(nblk + wn + r16) * 256;
    const unsigned short* B1 = B0 + 16 * 256;
    const int k0 = q * 8;

    f32x4 acc[2][2];
#pragma unroll
    for (int mi = 0; mi < 2; ++mi)
#pragma unroll
        for (int ni = 0; ni < 2; ++ni) acc[mi][ni] = (f32x4){0.f,0.f,0.f,0.f};

    f32x4 acur[2][2], anxt[2][2];
    bf16x8 bC[2];
#pragma unroll
    for (int f = 0; f < 2; ++f) {
        acur[f][0] = *(const f32x4*)(Af[f] + k0);
        acur[f][1] = *(const f32x4*)(Af[f] + k0 + 4);
    }
    bC[0] = *(const bf16x8*)(B0 + k0);
    bC[1] = *(const bf16x8*)(B1 + k0);

#pragma unroll
    for (int kk = 0; kk < 8; ++kk) {
        bf16x8 bN[2];
        if (kk < 7) {
            const int ko = k0 + (kk + 1) * 32;
#pragma unroll
            for (int f = 0; f < 2; ++f) {
                anxt[f][0] = *(const f32x4*)(Af[f] + ko);
                anxt[f][1] = *(const f32x4*)(Af[f] + ko + 4);
            }
            bN[0] = *(const bf16x8*)(B0 + ko);
            bN[1] = *(const bf16x8*)(B1 + ko);
        }
        const bf16x8 a0 = cvt8(acur[0][0], acur[0][1]);
        const bf16x8 a1 = cvt8(acur[1][0], acur[1][1]);
        acc[0][0] = MFMA16(a0, bC[0], acc[0][0]);
        acc[0][1] = MFMA16(a0, bC[1], acc[0][1]);
        acc[1][0] = MFMA16(a1, bC[0], acc[1][0]);
        acc[1][1] = MFMA16(a1, bC[1], acc[1][1]);
        bC[0] = bN[0]; bC[1] = bN[1];
#pragma unroll
        for (int f = 0; f < 2; ++f) { acur[f][0] = anxt[f][0]; acur[f][1] = anxt[f][1]; }
    }

#pragma unroll
    for (int mi = 0; mi < 2; ++mi)
#pragma unroll
        for (int ni = 0; ni < 2; ++ni)
#pragma unroll
            for (int r = 0; r < 4; ++r) {
                const int c = cblk + wc + mi * 16 + q * 4 + r;
                const int n = nblk + wn + ni * 16 + r16;
                const size_t idx = ((size_t)b * CQ_ + c) * NQ_ + n;
                out[idx] = g * acc[mi][ni][r] + Xb[(size_t)c * NQ_ + n];
            }
}

// -------------------------------------------------------------------------
extern "C" void kernel_launch(void* const* d_in, const int* in_sizes, int n_in,
                              void* d_out, int out_size, void* d_ws, size_t ws_size,
                              hipStream_t stream) {
    const float* x_q   = (const float*)d_in[0];
    const float* x_kv  = (const float*)d_in[1];
    const float* Wq    = (const float*)d_in[2];
    const float* Wk    = (const float*)d_in[3];
    const float* Wv    = (const float*)d_in[4];
    const float* Wo    = (const float*)d_in[5];
    const float* gamma = (const float*)d_in[6];
    float* out = (float*)d_out;

    char* ws = (char*)d_ws;
    // ws layout (bytes):
    //   xqt_bf bf16 [4][2048][256]        0 ..  4194304
    //   Gsum32 f32  [4][256][256]   4194304 ..  5242880   } zeroed by prep
    //   Nsum32 f32  [4][256][256]   5242880 ..  6291456   } (contiguous 2MB)
    //   P      bf16 [256][2048]     6291456 ..  7340032
    //   Qt     bf16 [8][256][256]   7340032 ..  8388608
    //   Zt     bf16 [4][256][2048]  8388608 .. 12582912
    unsigned short* xqt_bf = (unsigned short*)(ws);
    float*          Gsum32 = (float*)(ws + 4194304);
    float*          Nsum32 = (float*)(ws + 5242880);
    unsigned short* P      = (unsigned short*)(ws + 6291456);
    unsigned short* Qt     = (unsigned short*)(ws + 7340032);
    unsigned short* Zt     = (unsigned short*)(ws + 8388608);

    prep_kernel<<<dim3(656), 256, 0, stream>>>(x_q, Wq, Wk, Wv, Wo,
                                               xqt_bf, P, Qt, Gsum32);
    gram_kernel<<<dim3(8, 16, 4), 256, 0, stream>>>(x_kv, Gsum32);
    zgemm_kernel<<<dim3(16, 8, 4), 256, 0, stream>>>(Qt, Gsum32, Zt);
    ngemm_kernel<<<dim3(16, 8, 4), 256, 0, stream>>>(P, Zt, Nsum32);
    final_kernel<<<dim3(32, 4, 4), 256, 0, stream>>>(Nsum32, xqt_bf, x_q, gamma, out);
}